// Round 13
// baseline (251.489 us; speedup 1.0000x reference)
//
#include <hip/hip_runtime.h>
#include <hip/hip_bf16.h>
#include <math.h>

#define NB   32768
#define NM   2048
#define NEMB 128
#define NK   8
#define TAU  0.3f
#define FLT_BIG 3.402823466e38f

typedef __attribute__((ext_vector_type(8))) short bf16x8;
typedef __attribute__((ext_vector_type(4))) float f32x4;

// tanh-form GELU: x * sigmoid(2*0.79788456*(x+0.044715 x^3)), branch-free.
__device__ __forceinline__ float gelu_tanh(float x) {
    const float x2 = x * x;
    const float u  = fmaf(0.044715f, x2, 1.0f);
    const float a  = x * u * (-2.3022082f);          // -2*0.79788456*log2(e)
    const float e  = __builtin_amdgcn_exp2f(a);      // exp(-2t)
    const float r  = __builtin_amdgcn_rcpf(e + 1.0f);
    return x * r;                                    // x * sigmoid(2t)
}
// f32 pair -> packed bf16 (RNE): (bf16(hi)<<16)|bf16(lo), 1 v_cvt_pk_bf16_f32
__device__ __forceinline__ unsigned pack2(float lo, float hi) {
    __hip_bfloat162 b = __float22bfloat162_rn(make_float2(lo, hi));
    return *reinterpret_cast<unsigned*>(&b);
}

// DPP helpers: quad_perm xor1=0xB1, xor2=0x4E, row_half_mirror=0x141, row_mirror=0x140
template<int CTRL>
__device__ __forceinline__ unsigned dpp_umin(unsigned v) {
    const unsigned t = (unsigned)__builtin_amdgcn_update_dpp(0, (int)v, CTRL, 0xF, 0xF, true);
    return v < t ? v : t;
}
template<int CTRL>
__device__ __forceinline__ float dpp_fadd(float v) {
    const float t = __int_as_float(__builtin_amdgcn_update_dpp(0, __float_as_int(v), CTRL, 0xF, 0xF, true));
    return v + t;
}

// sorted top-3 insert (values via fmed3, payload via cndmask)
__device__ __forceinline__ void ins3(float (&bd)[3], unsigned (&bp)[3], float d, unsigned p) {
    const bool c0 = d < bd[0], c1 = d < bd[1], c2 = d < bd[2];
    const float n2 = __builtin_amdgcn_fmed3f(d, bd[1], bd[2]);
    const float n1 = __builtin_amdgcn_fmed3f(d, bd[0], bd[1]);
    const float n0 = fminf(d, bd[0]);
    bp[2] = c1 ? bp[1] : (c2 ? p : bp[2]);
    bp[1] = c0 ? bp[0] : (c1 ? p : bp[1]);
    bp[0] = c0 ? p : bp[0];
    bd[2] = n2; bd[1] = n1; bd[0] = n0;
}

// one wave-argmin-pop round; returns 1 if this lane's head was popped
template<int DEPTH>
__device__ __forceinline__ int ext_round(float (&ld)[DEPTH], unsigned (&lp)[DEPTH],
                                         float &td, unsigned &tp, const int lane) {
    const unsigned key = __float_as_uint(ld[0]);
    unsigned m = key;
    m = dpp_umin<0xB1>(m);  m = dpp_umin<0x4E>(m);
    m = dpp_umin<0x141>(m); m = dpp_umin<0x140>(m);
    { unsigned t = __shfl_xor(m, 16); m = m < t ? m : t;
      t = __shfl_xor(m, 32);          m = m < t ? m : t; }
    const unsigned long long mk = __ballot(key == m);
    const int src = __ffsll(mk) - 1;          // lowest lane holding the min
    td = __uint_as_float(m);
    tp = __shfl(lp[0], src);
    if (lane == src) {
#pragma unroll
        for (int j = 0; j < DEPTH - 1; ++j) { ld[j] = ld[j + 1]; lp[j] = lp[j + 1]; }
        ld[DEPTH - 1] = FLT_BIG;
        return 1;
    }
    return 0;
}

template<int DEPTH>
__device__ __forceinline__ int extract8(float (&ld)[DEPTH], unsigned (&lp)[DEPTH],
                                        float (&td)[8], unsigned (&tp)[8], const int lane) {
    int pops = 0;
#pragma unroll
    for (int k = 0; k < 8; ++k) pops += ext_round<DEPTH>(ld, lp, td[k], tp[k], lane);
    return pops;
}

// full-rescan exact fallback for one row (rare: P~2e-4/row)
__device__ __forceinline__ void fallback_row(const f32x4* a4, const float2 g,
                                             float (&td)[8], unsigned (&tp)[8], const int lane) {
    float    fd[8];
    unsigned fp[8];
#pragma unroll
    for (int i = 0; i < 8; ++i) { fd[i] = FLT_BIG; fp[i] = 0u; }
    for (int it = 0; it < 16; ++it) {
        const f32x4 vv = a4[it * 64 + lane];
#pragma unroll
        for (int h = 0; h < 2; ++h) {
            const float ax = h ? vv.z : vv.x;
            const float ay = h ? vv.w : vv.y;
            const float ddx = ax - g.x, ddy = ay - g.y;
            const float d = __fadd_rn(__fmul_rn(ddx, ddx), __fmul_rn(ddy, ddy));
            if (d < fd[7]) {
                const unsigned p = pack2(ax, ay);
#pragma unroll
                for (int j = 7; j >= 1; --j) {
                    const bool s1 = fd[j - 1] > d;
                    const bool s2 = fd[j] > d;
                    const float    nd = s1 ? fd[j - 1] : (s2 ? d : fd[j]);
                    const unsigned np = s1 ? fp[j - 1] : (s2 ? p : fp[j]);
                    fd[j] = nd; fp[j] = np;
                }
                if (fd[0] > d) { fd[0] = d; fp[0] = p; }
            }
        }
    }
    (void)extract8<8>(fd, fp, td, tp, lane);
}

// ---------------------------------------------------------------------------
// Fused kernel, 512 threads = 8 waves = 8 rows/block.
// R13 change: BLOCK-COOPERATIVE CONTIGUOUS STREAM. All 512 threads read one
// contiguous 8 KB super-chunk per iteration (thread t reads block_base +
// s*8KB + t*16B), sweeping the block's 128 KB linearly -> DRAM sees one
// contiguous window per block instead of 8 scattered 1 KB islands.
// Consequence: each thread sees 4 anchors of EACH of the 8 rows -> 8 per-row
// top-3 lists (statically indexed), per-wave top-8 extraction per row,
// cross-wave merge (8 waves x 8 cands) via LDS + depth-1 extraction by the
// owner wave. Per-lane depth-3-of-4 exactness fallback: owner-wave rescan.
// Phase 2 (softmax/L1/h1 pair tile/MFMA/epilogue) identical to R9.
// LDS 52.8 KB -> 3 blocks/CU; launch_bounds(512,5).
// ---------------------------------------------------------------------------
__global__ void __launch_bounds__(512, 5) fused_anchor_mlp(
    const float* __restrict__ Gl, const float* __restrict__ ancL,
    const float* __restrict__ W1, const float* __restrict__ b1,
    const float* __restrict__ W2, const float* __restrict__ b2,
    float* __restrict__ out)
{
    __shared__ uint4  w2s[2048];       // 128 rows x 16 slots bf16x8, 32 KB
    __shared__ uint4  h1s4[1024];      // 4 pairs x 16 k-rows x 16 slots, 16 KB
    __shared__ float4 b2s4[32];        // 512 B
    __shared__ float  wts[8][8];       // softmax weights per row
    __shared__ uint2  lmerge[8][8][8]; // [row][wave][k], 4 KB
    __shared__ int    fbflags[8];

    const int tid  = threadIdx.x;
    const int wave = tid >> 6;
    const int lane = tid & 63;
    const int pair = wave >> 1;
    const int half = wave & 1;
    const int rowbase = blockIdx.x << 3;

    // --- stage W2 (f32 -> bf16, phys_slot = slot ^ (row&7)) ---
    {
        const float4* w2f = reinterpret_cast<const float4*>(W2);
        for (int i = tid; i < 2048; i += 512) {
            const float4 lo = w2f[i * 2], hi = w2f[i * 2 + 1];
            uint4 u;
            u.x = pack2(lo.x, lo.y); u.y = pack2(lo.z, lo.w);
            u.z = pack2(hi.x, hi.y); u.w = pack2(hi.z, hi.w);
            w2s[(i & ~15) | ((i & 15) ^ ((i >> 4) & 7))] = u;
        }
        if (tid < 32) b2s4[tid] = reinterpret_cast<const float4*>(b2)[tid];
    }
    // first __syncthreads below (after lmerge writes) covers this staging

    // --- query points for all 8 rows (block-uniform addresses) ---
    const float2* Gl2 = reinterpret_cast<const float2*>(Gl);
    float2 g8[8];
#pragma unroll
    for (int r = 0; r < 8; ++r) g8[r] = Gl2[rowbase + r];

    // --- phase 1: contiguous cooperative stream, 8 per-row top-3 lists ---
    const f32x4* ab = reinterpret_cast<const f32x4*>(ancL) + (size_t)rowbase * (NM / 2);

    float    bd[8][3];
    unsigned bp[8][3];
#pragma unroll
    for (int r = 0; r < 8; ++r)
#pragma unroll
        for (int i = 0; i < 3; ++i) { bd[r][i] = FLT_BIG; bp[r][i] = 0u; }

    f32x4 buf[2];
    buf[0] = ab[tid];
    buf[1] = ab[512 + tid];

#pragma unroll
    for (int s = 0; s < 16; ++s) {
        const f32x4 v = buf[s & 1];                  // static after full unroll
        if (s + 2 < 16) buf[s & 1] = ab[(s + 2) * 512 + tid];
        const int r = s >> 1;                        // static row index
        const float dx0 = v.x - g8[r].x, dy0 = v.y - g8[r].y;
        const float dx1 = v.z - g8[r].x, dy1 = v.w - g8[r].y;
        // bit-identical to numpy: no fma contraction
        const float d0 = __fadd_rn(__fmul_rn(dx0, dx0), __fmul_rn(dy0, dy0));
        const float d1 = __fadd_rn(__fmul_rn(dx1, dx1), __fmul_rn(dy1, dy1));
        ins3(bd[r], bp[r], d0, pack2(v.x, v.y));
        ins3(bd[r], bp[r], d1, pack2(v.z, v.w));
    }

    // --- per-wave extraction: wave-top-8 for each of the 8 rows -> LDS ---
    int fbmask = 0;
#pragma unroll
    for (int r = 0; r < 8; ++r) {
        int pops = 0;
#pragma unroll
        for (int k = 0; k < 8; ++k) {
            float etd; unsigned etp;
            pops += ext_round<3>(bd[r], bp[r], etd, etp, lane);
            if (lane == k) lmerge[r][wave][k] = make_uint2(__float_as_uint(etd), etp);
        }
        // lane kept top-3 of its 4 candidates; popping all 3 hides its 4th
        if (__ballot(pops == 3)) fbmask |= (1 << r);
    }
    if (lane == 0) fbflags[wave] = fbmask;
    __syncthreads();   // covers w2s/b2s4 staging + lmerge + fbflags

    // --- cross-wave merge: wave w owns row rowbase+w; 64 candidates ---
    const uint2 cand = lmerge[wave][lane >> 3][lane & 7];
    float    md[1] = { __uint_as_float(cand.x) };
    unsigned mp[1] = { cand.y };
    float    td[8];
    unsigned tp[8];
    (void)extract8<1>(md, mp, td, tp, lane);

    // --- exactness fallback (P~2e-4/row): owner wave rescans its row ---
    int allfb = 0;
#pragma unroll
    for (int w = 0; w < 8; ++w) allfb |= fbflags[w];
    if ((allfb >> wave) & 1) {
        const f32x4* aOwn = reinterpret_cast<const f32x4*>(ancL)
                            + (size_t)(rowbase + wave) * (NM / 2);
        const float2 gOwn = Gl2[rowbase + wave];
        fallback_row(aOwn, gOwn, td, tp, lane);
    }

    // --- softmax(d2/tau); publish weights for the pair epilogue ---
    const float mx = td[7];
    float ek[8], ssum = 0.f;
#pragma unroll
    for (int k = 0; k < 8; ++k) { ek[k] = __expf((td[k] - mx) * (1.0f / TAU)); ssum += ek[k]; }
    const float inv = 1.0f / ssum;
    float wv = 0.f;
#pragma unroll
    for (int k = 0; k < 8; ++k) wv = (lane == k) ? ek[k] * inv : wv;
    if (lane < 8) wts[wave][lane] = wv;

    // --- layer 1: lane owns e0=2*lane, e1=2*lane+1; write to pair tile ---
    const float4 w1v = reinterpret_cast<const float4*>(W1)[lane];
    const float2 b1v = reinterpret_cast<const float2*>(b1)[lane];
    unsigned* h1w = reinterpret_cast<unsigned*>(h1s4 + (pair << 8));
#pragma unroll
    for (int k = 0; k < 8; ++k) {
        const unsigned pk = tp[k];
        const float ax = __uint_as_float(pk << 16);          // bf16 -> f32 exact
        const float ay = __uint_as_float(pk & 0xFFFF0000u);
        const float x0 = fmaf(ax, w1v.x, fmaf(ay, w1v.y, b1v.x));
        const float x1 = fmaf(ax, w1v.z, fmaf(ay, w1v.w, b1v.y));
        const int r = (half << 3) + k;   // row in pair tile; swizzle key = r&7 = k
        h1w[(r << 6) + ((((lane >> 2) ^ k) << 2) | (lane & 3))] = pack2(gelu_tanh(x0), gelu_tanh(x1));
    }
    __syncthreads();

    // --- B fragments from pair tile: col n = lane&15 (0..7 even, 8..15 odd) ---
    const uint4* h1b = h1s4 + (pair << 8);
    const int bslot = lane >> 4, bxor = lane & 7, brow = (lane & 15) * 16;
    bf16x8 bq0 = __builtin_bit_cast(bf16x8, h1b[brow + (( 0 + bslot) ^ bxor)]);
    bf16x8 bq1 = __builtin_bit_cast(bf16x8, h1b[brow + (( 4 + bslot) ^ bxor)]);
    bf16x8 bq2 = __builtin_bit_cast(bf16x8, h1b[brow + (( 8 + bslot) ^ bxor)]);
    bf16x8 bq3 = __builtin_bit_cast(bf16x8, h1b[brow + ((12 + bslot) ^ bxor)]);

    // weight for this lane's D column
    const float wsel = wts[(pair << 1) | ((lane >> 3) & 1)][lane & 7];

    // --- MFMA: this wave does f-tiles half*4 .. half*4+3 for BOTH rows ---
#pragma unroll 2
    for (int i = 0; i < 4; ++i) {
        const int ft = (half << 2) + i;
        const int arow = (ft * 16 + (lane & 15)) * 16;
        f32x4 acc = {0.f, 0.f, 0.f, 0.f};
        acc = __builtin_amdgcn_mfma_f32_16x16x32_bf16(
                  __builtin_bit_cast(bf16x8, w2s[arow + (( 0 + bslot) ^ bxor)]), bq0, acc, 0, 0, 0);
        acc = __builtin_amdgcn_mfma_f32_16x16x32_bf16(
                  __builtin_bit_cast(bf16x8, w2s[arow + (( 4 + bslot) ^ bxor)]), bq1, acc, 0, 0, 0);
        acc = __builtin_amdgcn_mfma_f32_16x16x32_bf16(
                  __builtin_bit_cast(bf16x8, w2s[arow + (( 8 + bslot) ^ bxor)]), bq2, acc, 0, 0, 0);
        acc = __builtin_amdgcn_mfma_f32_16x16x32_bf16(
                  __builtin_bit_cast(bf16x8, w2s[arow + ((12 + bslot) ^ bxor)]), bq3, acc, 0, 0, 0);

        // D: row f = ft*16 + (lane>>4)*4 + j, col = lane&15
        const float4 b2v = b2s4[ft * 4 + (lane >> 4)];
        float s0 = gelu_tanh(acc[0] + b2v.x) * wsel;
        float s1 = gelu_tanh(acc[1] + b2v.y) * wsel;
        float s2 = gelu_tanh(acc[2] + b2v.z) * wsel;
        float s3 = gelu_tanh(acc[3] + b2v.w) * wsel;
        // sum over the 8 k-slots (lanes sharing lane&~7) via DPP adds
        s0 = dpp_fadd<0xB1>(s0); s0 = dpp_fadd<0x4E>(s0); s0 = dpp_fadd<0x141>(s0);
        s1 = dpp_fadd<0xB1>(s1); s1 = dpp_fadd<0x4E>(s1); s1 = dpp_fadd<0x141>(s1);
        s2 = dpp_fadd<0xB1>(s2); s2 = dpp_fadd<0x4E>(s2); s2 = dpp_fadd<0x141>(s2);
        s3 = dpp_fadd<0xB1>(s3); s3 = dpp_fadd<0x4E>(s3); s3 = dpp_fadd<0x141>(s3);
        if ((lane & 7) == 0) {
            const int which = (lane >> 3) & 1;   // 0 = row even, 1 = row odd
            const size_t ob = (size_t)(rowbase + (pair << 1) + which) * NEMB
                              + ft * 16 + ((lane >> 4) << 2);
            *reinterpret_cast<float4*>(&out[ob]) = make_float4(s0, s1, s2, s3);
        }
    }
}

extern "C" void kernel_launch(void* const* d_in, const int* in_sizes, int n_in,
                              void* d_out, int out_size, void* d_ws, size_t ws_size,
                              hipStream_t stream)
{
    const float* Gl  = (const float*)d_in[0];
    const float* anc = (const float*)d_in[1];
    const float* W1  = (const float*)d_in[2];
    const float* b1  = (const float*)d_in[3];
    const float* W2  = (const float*)d_in[4];
    const float* b2  = (const float*)d_in[5];
    float* outp = (float*)d_out;

    fused_anchor_mlp<<<NB / 8, 512, 0, stream>>>(Gl, anc, W1, b1, W2, b2, outp);
}

// Round 14
// 134.339 us; speedup vs baseline: 1.8720x; 1.8720x over previous
//
#include <hip/hip_runtime.h>
#include <hip/hip_bf16.h>
#include <math.h>

#define NB   32768
#define NM   2048
#define NEMB 128
#define NK   8
#define TAU  0.3f
#define FLT_BIG 3.402823466e38f

typedef __attribute__((ext_vector_type(8))) short bf16x8;
typedef __attribute__((ext_vector_type(4))) float f32x4;

// tanh-form GELU: x * sigmoid(2*0.79788456*(x+0.044715 x^3)), branch-free.
__device__ __forceinline__ float gelu_tanh(float x) {
    const float x2 = x * x;
    const float u  = fmaf(0.044715f, x2, 1.0f);
    const float a  = x * u * (-2.3022082f);          // -2*0.79788456*log2(e)
    const float e  = __builtin_amdgcn_exp2f(a);      // exp(-2t)
    const float r  = __builtin_amdgcn_rcpf(e + 1.0f);
    return x * r;                                    // x * sigmoid(2t)
}
// f32 pair -> packed bf16 (RNE): (bf16(hi)<<16)|bf16(lo), 1 v_cvt_pk_bf16_f32
__device__ __forceinline__ unsigned pack2(float lo, float hi) {
    __hip_bfloat162 b = __float22bfloat162_rn(make_float2(lo, hi));
    return *reinterpret_cast<unsigned*>(&b);
}

// DPP helpers: quad_perm xor1=0xB1, xor2=0x4E, row_half_mirror=0x141, row_mirror=0x140
template<int CTRL>
__device__ __forceinline__ unsigned dpp_umin(unsigned v) {
    const unsigned t = (unsigned)__builtin_amdgcn_update_dpp(0, (int)v, CTRL, 0xF, 0xF, true);
    return v < t ? v : t;
}
template<int CTRL>
__device__ __forceinline__ float dpp_fadd(float v) {
    const float t = __int_as_float(__builtin_amdgcn_update_dpp(0, __float_as_int(v), CTRL, 0xF, 0xF, true));
    return v + t;
}

// sorted top-3 insert (values via fmed3, payload via cndmask)
__device__ __forceinline__ void ins3(float (&bd)[3], unsigned (&bp)[3], float d, unsigned p) {
    const bool c0 = d < bd[0], c1 = d < bd[1], c2 = d < bd[2];
    const float n2 = __builtin_amdgcn_fmed3f(d, bd[1], bd[2]);
    const float n1 = __builtin_amdgcn_fmed3f(d, bd[0], bd[1]);
    const float n0 = fminf(d, bd[0]);
    bp[2] = c1 ? bp[1] : (c2 ? p : bp[2]);
    bp[1] = c0 ? bp[0] : (c1 ? p : bp[1]);
    bp[0] = c0 ? p : bp[0];
    bd[2] = n2; bd[1] = n1; bd[0] = n0;
}

// one wave-argmin-pop round; returns 1 if this lane's head was popped
template<int DEPTH>
__device__ __forceinline__ int ext_round(float (&ld)[DEPTH], unsigned (&lp)[DEPTH],
                                         float &td, unsigned &tp, const int lane) {
    const unsigned key = __float_as_uint(ld[0]);
    unsigned m = key;
    m = dpp_umin<0xB1>(m);  m = dpp_umin<0x4E>(m);
    m = dpp_umin<0x141>(m); m = dpp_umin<0x140>(m);
    { unsigned t = __shfl_xor(m, 16); m = m < t ? m : t;
      t = __shfl_xor(m, 32);          m = m < t ? m : t; }
    const unsigned long long mk = __ballot(key == m);
    const int src = __ffsll(mk) - 1;          // lowest lane holding the min
    td = __uint_as_float(m);
    tp = __shfl(lp[0], src);
    if (lane == src) {
#pragma unroll
        for (int j = 0; j < DEPTH - 1; ++j) { ld[j] = ld[j + 1]; lp[j] = lp[j + 1]; }
        ld[DEPTH - 1] = FLT_BIG;
        return 1;
    }
    return 0;
}

template<int DEPTH>
__device__ __forceinline__ int extract8(float (&ld)[DEPTH], unsigned (&lp)[DEPTH],
                                        float (&td)[8], unsigned (&tp)[8], const int lane) {
    int pops = 0;
#pragma unroll
    for (int k = 0; k < 8; ++k) pops += ext_round<DEPTH>(ld, lp, td[k], tp[k], lane);
    return pops;
}

// full-rescan exact fallback for one row (rare: P~1.4%/row)
__device__ __forceinline__ void fallback_row(const f32x4* a4, const float2 g,
                                             float (&td)[8], unsigned (&tp)[8], const int lane) {
    float    fd[8];
    unsigned fp[8];
#pragma unroll
    for (int i = 0; i < 8; ++i) { fd[i] = FLT_BIG; fp[i] = 0u; }
    for (int it = 0; it < 16; ++it) {
        const f32x4 vv = a4[it * 64 + lane];
#pragma unroll
        for (int h = 0; h < 2; ++h) {
            const float ax = h ? vv.z : vv.x;
            const float ay = h ? vv.w : vv.y;
            const float ddx = ax - g.x, ddy = ay - g.y;
            const float d = __fadd_rn(__fmul_rn(ddx, ddx), __fmul_rn(ddy, ddy));
            if (d < fd[7]) {
                const unsigned p = pack2(ax, ay);
#pragma unroll
                for (int j = 7; j >= 1; --j) {
                    const bool s1 = fd[j - 1] > d;
                    const bool s2 = fd[j] > d;
                    const float    nd = s1 ? fd[j - 1] : (s2 ? d : fd[j]);
                    const unsigned np = s1 ? fp[j - 1] : (s2 ? p : fp[j]);
                    fd[j] = nd; fp[j] = np;
                }
                if (fd[0] > d) { fd[0] = d; fp[0] = p; }
            }
        }
    }
    (void)extract8<8>(fd, fp, td, tp, lane);
}

// ---------------------------------------------------------------------------
// Fused kernel, 512 threads = 8 waves = 8 rows/block. (Best structure, R9:
// 132.8 us, replicated exactly by R12. Read delivery pinned at 4.04 TB/s
// across all tested structures -> treated as the read-path roofline.)
// Phase 1: 3-deep rolling prefetch, unconditional per-lane sorted top-3
//   (fmed3 + packed-bf16 payload), DPP-argmin extraction x8, full-rescan
//   fallback (P~1.4%/row).
// Phase 2: softmax weights -> layer1 tanh-GELU -> bf16 h1 pair tile (LDS,
//   swizzled) -> mfma_f32_16x16x32_bf16 (A=W2 bf16 LDS) -> fused epilogue
//   with DPP 8-lane k-reduction. Row-pairing: B cols 0..7 even row, 8..15 odd.
// ---------------------------------------------------------------------------
__global__ void __launch_bounds__(512, 6) fused_anchor_mlp(
    const float* __restrict__ Gl, const float* __restrict__ ancL,
    const float* __restrict__ W1, const float* __restrict__ b1,
    const float* __restrict__ W2, const float* __restrict__ b2,
    float* __restrict__ out)
{
    __shared__ uint4  w2s[2048];      // 128 rows x 16 slots bf16x8, 32 KB
    __shared__ uint4  h1s4[1024];     // 4 pairs x 16 k-rows x 16 slots, 16 KB
    __shared__ float4 b2s4[32];       // 512 B
    __shared__ float  wts[8][8];      // softmax weights per row

    const int tid  = threadIdx.x;
    const int wave = tid >> 6;
    const int lane = tid & 63;
    const int pair = wave >> 1;
    const int half = wave & 1;
    const int rowbase = blockIdx.x << 3;
    const int row  = rowbase + wave;

    // --- stage W2 (f32 -> bf16, phys_slot = slot ^ (row&7)) ---
    {
        const float4* w2f = reinterpret_cast<const float4*>(W2);
        for (int i = tid; i < 2048; i += 512) {
            const float4 lo = w2f[i * 2], hi = w2f[i * 2 + 1];
            uint4 u;
            u.x = pack2(lo.x, lo.y); u.y = pack2(lo.z, lo.w);
            u.z = pack2(hi.x, hi.y); u.w = pack2(hi.z, hi.w);
            w2s[(i & ~15) | ((i & 15) ^ ((i >> 4) & 7))] = u;
        }
        if (tid < 32) b2s4[tid] = reinterpret_cast<const float4*>(b2)[tid];
    }
    // single __syncthreads below (after h1 writes) covers all staging

    // --- phase 1: stream anchors, 3-deep rolling prefetch, top-3/lane ---
    const float2 g = reinterpret_cast<const float2*>(Gl)[row];
    const f32x4* a4 = reinterpret_cast<const f32x4*>(ancL) + (size_t)row * (NM / 2);

    float    bd[3];
    unsigned bp[3];
#pragma unroll
    for (int i = 0; i < 3; ++i) { bd[i] = FLT_BIG; bp[i] = 0u; }

    f32x4 buf[3];
#pragma unroll
    for (int j = 0; j < 3; ++j) buf[j] = a4[j * 64 + lane];

#pragma unroll
    for (int it = 0; it < 16; ++it) {
        const int slot = it % 3;                 // static after full unroll
        const f32x4 v = buf[slot];
        if (it + 3 < 16) buf[slot] = a4[(it + 3) * 64 + lane];
        const float dx0 = v.x - g.x, dy0 = v.y - g.y;
        const float dx1 = v.z - g.x, dy1 = v.w - g.y;
        // bit-identical to numpy: no fma contraction
        const float d0 = __fadd_rn(__fmul_rn(dx0, dx0), __fmul_rn(dy0, dy0));
        const float d1 = __fadd_rn(__fmul_rn(dx1, dx1), __fmul_rn(dy1, dy1));
        ins3(bd, bp, d0, pack2(v.x, v.y));
        ins3(bd, bp, d1, pack2(v.z, v.w));
    }

    // --- extraction: 8 rounds of DPP-argmin over lane heads ---
    float    td[8];
    unsigned tp[8];
    const int pops = extract8<3>(bd, bp, td, tp, lane);

    // --- exactness fallback (P~1.4%/row): some lane had all 3 popped ---
    if (__ballot(pops == 3)) fallback_row(a4, g, td, tp, lane);

    // --- softmax(d2/tau); publish weights for the pair epilogue ---
    const float mx = td[7];
    float ek[8], ssum = 0.f;
#pragma unroll
    for (int k = 0; k < 8; ++k) { ek[k] = __expf((td[k] - mx) * (1.0f / TAU)); ssum += ek[k]; }
    const float inv = 1.0f / ssum;
    float wv = 0.f;
#pragma unroll
    for (int k = 0; k < 8; ++k) wv = (lane == k) ? ek[k] * inv : wv;
    if (lane < 8) wts[wave][lane] = wv;

    // --- layer 1: lane owns e0=2*lane, e1=2*lane+1; write to pair tile ---
    const float4 w1v = reinterpret_cast<const float4*>(W1)[lane];
    const float2 b1v = reinterpret_cast<const float2*>(b1)[lane];
    unsigned* h1w = reinterpret_cast<unsigned*>(h1s4 + (pair << 8));
#pragma unroll
    for (int k = 0; k < 8; ++k) {
        const unsigned pk = tp[k];
        const float ax = __uint_as_float(pk << 16);          // bf16 -> f32 exact
        const float ay = __uint_as_float(pk & 0xFFFF0000u);
        const float x0 = fmaf(ax, w1v.x, fmaf(ay, w1v.y, b1v.x));
        const float x1 = fmaf(ax, w1v.z, fmaf(ay, w1v.w, b1v.y));
        const int r = (half << 3) + k;   // row in pair tile; swizzle key = r&7 = k
        h1w[(r << 6) + ((((lane >> 2) ^ k) << 2) | (lane & 3))] = pack2(gelu_tanh(x0), gelu_tanh(x1));
    }
    __syncthreads();

    // --- B fragments from pair tile: col n = lane&15 (0..7 even, 8..15 odd) ---
    const uint4* h1b = h1s4 + (pair << 8);
    const int bslot = lane >> 4, bxor = lane & 7, brow = (lane & 15) * 16;
    bf16x8 bq0 = __builtin_bit_cast(bf16x8, h1b[brow + (( 0 + bslot) ^ bxor)]);
    bf16x8 bq1 = __builtin_bit_cast(bf16x8, h1b[brow + (( 4 + bslot) ^ bxor)]);
    bf16x8 bq2 = __builtin_bit_cast(bf16x8, h1b[brow + (( 8 + bslot) ^ bxor)]);
    bf16x8 bq3 = __builtin_bit_cast(bf16x8, h1b[brow + ((12 + bslot) ^ bxor)]);

    // weight for this lane's D column
    const float wsel = wts[(pair << 1) | ((lane >> 3) & 1)][lane & 7];

    // --- MFMA: this wave does f-tiles half*4 .. half*4+3 for BOTH rows ---
#pragma unroll 2
    for (int i = 0; i < 4; ++i) {
        const int ft = (half << 2) + i;
        const int arow = (ft * 16 + (lane & 15)) * 16;
        f32x4 acc = {0.f, 0.f, 0.f, 0.f};
        acc = __builtin_amdgcn_mfma_f32_16x16x32_bf16(
                  __builtin_bit_cast(bf16x8, w2s[arow + (( 0 + bslot) ^ bxor)]), bq0, acc, 0, 0, 0);
        acc = __builtin_amdgcn_mfma_f32_16x16x32_bf16(
                  __builtin_bit_cast(bf16x8, w2s[arow + (( 4 + bslot) ^ bxor)]), bq1, acc, 0, 0, 0);
        acc = __builtin_amdgcn_mfma_f32_16x16x32_bf16(
                  __builtin_bit_cast(bf16x8, w2s[arow + (( 8 + bslot) ^ bxor)]), bq2, acc, 0, 0, 0);
        acc = __builtin_amdgcn_mfma_f32_16x16x32_bf16(
                  __builtin_bit_cast(bf16x8, w2s[arow + ((12 + bslot) ^ bxor)]), bq3, acc, 0, 0, 0);

        // D: row f = ft*16 + (lane>>4)*4 + j, col = lane&15
        const float4 b2v = b2s4[ft * 4 + (lane >> 4)];
        float s0 = gelu_tanh(acc[0] + b2v.x) * wsel;
        float s1 = gelu_tanh(acc[1] + b2v.y) * wsel;
        float s2 = gelu_tanh(acc[2] + b2v.z) * wsel;
        float s3 = gelu_tanh(acc[3] + b2v.w) * wsel;
        // sum over the 8 k-slots (lanes sharing lane&~7) via DPP adds
        s0 = dpp_fadd<0xB1>(s0); s0 = dpp_fadd<0x4E>(s0); s0 = dpp_fadd<0x141>(s0);
        s1 = dpp_fadd<0xB1>(s1); s1 = dpp_fadd<0x4E>(s1); s1 = dpp_fadd<0x141>(s1);
        s2 = dpp_fadd<0xB1>(s2); s2 = dpp_fadd<0x4E>(s2); s2 = dpp_fadd<0x141>(s2);
        s3 = dpp_fadd<0xB1>(s3); s3 = dpp_fadd<0x4E>(s3); s3 = dpp_fadd<0x141>(s3);
        if ((lane & 7) == 0) {
            const int which = (lane >> 3) & 1;   // 0 = row even, 1 = row odd
            const size_t ob = (size_t)(rowbase + (pair << 1) + which) * NEMB
                              + ft * 16 + ((lane >> 4) << 2);
            *reinterpret_cast<float4*>(&out[ob]) = make_float4(s0, s1, s2, s3);
        }
    }
}

extern "C" void kernel_launch(void* const* d_in, const int* in_sizes, int n_in,
                              void* d_out, int out_size, void* d_ws, size_t ws_size,
                              hipStream_t stream)
{
    const float* Gl  = (const float*)d_in[0];
    const float* anc = (const float*)d_in[1];
    const float* W1  = (const float*)d_in[2];
    const float* b1  = (const float*)d_in[3];
    const float* W2  = (const float*)d_in[4];
    const float* b2  = (const float*)d_in[5];
    float* outp = (float*)d_out;

    fused_anchor_mlp<<<NB / 8, 512, 0, stream>>>(Gl, anc, W1, b1, W2, b2, outp);
}